// Round 8
// baseline (1145.189 us; speedup 1.0000x reference)
//
#include <hip/hip_runtime.h>
#include <hip/hip_bf16.h>
#include <math.h>

// ---------------- constants ----------------
constexpr int Bsz = 4, T = 2048, D = 512, H = 8, Lnum = 6, DFF = 2048, DK = 64;
constexpr int QS2 = 1024;                       // qkv row stride (q at 0, k at 512; v goes to vt)
constexpr float K2 = 0.08838834764831845f / 1.5f;  // softmax exponent scale (folded into q)

typedef __attribute__((ext_vector_type(8))) short svec8;   // 8 bf16 (4 VGPRs)
typedef __attribute__((ext_vector_type(4))) float fvec4;   // 4 fp32 acc

__device__ __forceinline__ fvec4 mfma16(svec8 a, svec8 b, fvec4 c) {
    return __builtin_amdgcn_mfma_f32_16x16x32_bf16(a, b, c, 0, 0, 0);
}
__device__ __forceinline__ unsigned short f2b(float f) {
    unsigned int u = __float_as_uint(f);
    u += 0x7fffu + ((u >> 16) & 1u);
    return (unsigned short)(u >> 16);
}
__device__ __forceinline__ unsigned int pk2b(float a, float b) {
    __hip_bfloat162 h = __float22bfloat162_rn(float2{a, b});
    return *(unsigned int*)&h;
}
__device__ __forceinline__ float wave_red_sum(float v) {
    for (int o = 32; o > 0; o >>= 1) v += __shfl_down(v, o, 64);
    return __shfl(v, 0, 64);
}
// async global->LDS, 16B per lane; lds base must be wave-uniform (HW adds lane*16)
__device__ __forceinline__ void glds16(const unsigned short* g, unsigned short* l) {
    __builtin_amdgcn_global_load_lds(
        (const __attribute__((address_space(1))) unsigned int*)g,
        (__attribute__((address_space(3))) unsigned int*)l, 16, 0, 0);
}
// swizzled-tile fragment read: 64-wide rows, chunk kq of row r at slot kq^(r&7)
#define FRAG(buf, row, kq) (*(const svec8*)((buf) + (((row) << 6) | ((((kq) ^ ((row) & 7))) << 3))))

// ---------------- embed (fp32 h) ----------------
__global__ __launch_bounds__(64)
void embed_kernel(const float* __restrict__ x, const float* __restrict__ ip_w,
                  const float* __restrict__ ip_b, const float* __restrict__ g,
                  const float* __restrict__ bta, const float* __restrict__ pos,
                  const float* __restrict__ pad_tok, float* __restrict__ h)
{
    int row = blockIdx.x;
    int t = row & (T - 1);
    int lane = threadIdx.x;
    float xv = x[row];
    float xc = fminf(fmaxf(xv, -10.f), 10.f);
    bool pad = (xc == -1.0f);
    float pre[8];
    float s = 0.f, s2 = 0.f;
#pragma unroll
    for (int j = 0; j < 8; j++) {
        int d = j * 64 + lane;
        float p = xc * ip_w[d] + ip_b[d];
        pre[j] = p; s += p; s2 += p * p;
    }
    s = wave_red_sum(s); s2 = wave_red_sum(s2);
    float m = s * (1.f / 512.f);
    float var = s2 * (1.f / 512.f) - m * m;
    float rstd = 1.f / sqrtf(var + 1e-5f);
#pragma unroll
    for (int j = 0; j < 8; j++) {
        int d = j * 64 + lane;
        float hv = (pre[j] - m) * rstd * g[d] + bta[d] + 0.1f * pos[(size_t)t * D + d];
        if (pad) hv = pad_tok[d];
        h[(size_t)row * D + d] = hv;
    }
}

// ---------------- LayerNorm fp32 -> fp32 (final), 4 rows/block ----------------
__global__ __launch_bounds__(256)
void ln_kernel(const float* __restrict__ in, float* __restrict__ out,
               const float* __restrict__ g, const float* __restrict__ b)
{
    int row = blockIdx.x * 4 + (threadIdx.x >> 6);
    int lane = threadIdx.x & 63;
    const float* r = in + (size_t)row * D;
    float4 v0 = ((const float4*)r)[lane];
    float4 v1 = ((const float4*)r)[lane + 64];
    float s = v0.x + v0.y + v0.z + v0.w + v1.x + v1.y + v1.z + v1.w;
    float s2 = v0.x*v0.x + v0.y*v0.y + v0.z*v0.z + v0.w*v0.w
             + v1.x*v1.x + v1.y*v1.y + v1.z*v1.z + v1.w*v1.w;
    s = wave_red_sum(s); s2 = wave_red_sum(s2);
    float m = s * (1.f / 512.f);
    float var = s2 * (1.f / 512.f) - m * m;
    float rstd = 1.f / sqrtf(var + 1e-5f);
    float4 g0 = ((const float4*)g)[lane], g1 = ((const float4*)g)[lane + 64];
    float4 b0 = ((const float4*)b)[lane], b1 = ((const float4*)b)[lane + 64];
    float4 o0, o1;
    o0.x = (v0.x - m) * rstd * g0.x + b0.x; o0.y = (v0.y - m) * rstd * g0.y + b0.y;
    o0.z = (v0.z - m) * rstd * g0.z + b0.z; o0.w = (v0.w - m) * rstd * g0.w + b0.w;
    o1.x = (v1.x - m) * rstd * g1.x + b1.x; o1.y = (v1.y - m) * rstd * g1.y + b1.y;
    o1.z = (v1.z - m) * rstd * g1.z + b1.z; o1.w = (v1.w - m) * rstd * g1.w + b1.w;
    ((float4*)(out + (size_t)row * D))[lane] = o0;
    ((float4*)(out + (size_t)row * D))[lane + 64] = o1;
}

// ---------------- device LN fp32 -> bf16 helper (one wave, one row) ----------------
__device__ __forceinline__ void ln_row_bf16(const float* __restrict__ in, unsigned short* __restrict__ out,
                                            const float* __restrict__ g, const float* __restrict__ b,
                                            int row, int lane)
{
    const float* r = in + (size_t)row * D;
    float4 v0 = ((const float4*)r)[lane];
    float4 v1 = ((const float4*)r)[lane + 64];
    float s = v0.x + v0.y + v0.z + v0.w + v1.x + v1.y + v1.z + v1.w;
    float s2 = v0.x*v0.x + v0.y*v0.y + v0.z*v0.z + v0.w*v0.w
             + v1.x*v1.x + v1.y*v1.y + v1.z*v1.z + v1.w*v1.w;
    s = wave_red_sum(s); s2 = wave_red_sum(s2);
    float m = s * (1.f / 512.f);
    float var = s2 * (1.f / 512.f) - m * m;
    float rstd = 1.f / sqrtf(var + 1e-5f);
    float4 g0 = ((const float4*)g)[lane], g1 = ((const float4*)g)[lane + 64];
    float4 b0 = ((const float4*)b)[lane], b1 = ((const float4*)b)[lane + 64];
    unsigned short o0[4], o1[4];
    o0[0] = f2b((v0.x - m) * rstd * g0.x + b0.x); o0[1] = f2b((v0.y - m) * rstd * g0.y + b0.y);
    o0[2] = f2b((v0.z - m) * rstd * g0.z + b0.z); o0[3] = f2b((v0.w - m) * rstd * g0.w + b0.w);
    o1[0] = f2b((v1.x - m) * rstd * g1.x + b1.x); o1[1] = f2b((v1.y - m) * rstd * g1.y + b1.y);
    o1[2] = f2b((v1.z - m) * rstd * g1.z + b1.z); o1[3] = f2b((v1.w - m) * rstd * g1.w + b1.w);
    *(uint2*)(out + (size_t)row * D + lane * 4) = *(uint2*)o0;
    *(uint2*)(out + (size_t)row * D + 256 + lane * 4) = *(uint2*)o1;
}

__global__ __launch_bounds__(256)
void ln_bf16_kernel(const float* __restrict__ in, unsigned short* __restrict__ out,
                    const float* __restrict__ g, const float* __restrict__ b)
{
    ln_row_bf16(in, out, g, b, blockIdx.x * 4 + (threadIdx.x >> 6), threadIdx.x & 63);
}

// ---------------- fused per-layer prep: wconv (bid<3072) + ln1 (bid in [3072,5120)) ----------------
__global__ __launch_bounds__(256)
void prep_kernel(const float* __restrict__ wq, const float* __restrict__ wk,
                 const float* __restrict__ wv, const float* __restrict__ wo,
                 const float* __restrict__ w1, const float* __restrict__ w2,
                 unsigned short* __restrict__ oq, unsigned short* __restrict__ ok,
                 unsigned short* __restrict__ ov, unsigned short* __restrict__ oo,
                 unsigned short* __restrict__ o1, unsigned short* __restrict__ o2,
                 const float* __restrict__ hin, unsigned short* __restrict__ lnout,
                 const float* __restrict__ ln_g, const float* __restrict__ ln_b)
{
    __shared__ float tile[32][33];
    int bid = blockIdx.x;
    if (bid >= 3072) {
        // 2048 blocks x 4 rows = 8192 rows  (R7 bug: was 512 blocks -> only 1/4 of rows)
        int row = (bid - 3072) * 4 + (threadIdx.x >> 6);
        ln_row_bf16(hin, lnout, ln_g, ln_b, row, threadIdx.x & 63);
        return;
    }
    const float* in; unsigned short* out; int K, N, kt, nt;
    if (bid < 1024) {
        int sel = bid >> 8, loc = bid & 255;
        in  = sel == 0 ? wq : sel == 1 ? wk : sel == 2 ? wv : wo;
        out = sel == 0 ? oq : sel == 1 ? ok : sel == 2 ? ov : oo;
        K = 512; N = 512; kt = loc >> 4; nt = loc & 15;
    } else if (bid < 2048) {
        int loc = bid - 1024; in = w1; out = o1; K = 512; N = 2048; kt = loc >> 6; nt = loc & 63;
    } else {
        int loc = bid - 2048; in = w2; out = o2; K = 2048; N = 512; kt = loc >> 4; nt = loc & 15;
    }
    int k0 = kt * 32, n0 = nt * 32;
    int t = threadIdx.x;
    int kr = t >> 3, nc = (t & 7) * 4;
    float4 v = *(const float4*)(in + (size_t)(k0 + kr) * N + n0 + nc);
    tile[kr][nc] = v.x; tile[kr][nc + 1] = v.y; tile[kr][nc + 2] = v.z; tile[kr][nc + 3] = v.w;
    __syncthreads();
    unsigned short o[4];
#pragma unroll
    for (int i = 0; i < 4; i++) o[i] = f2b(tile[nc + i][kr]);
    *(uint2*)(out + (size_t)(n0 + kr) * K + k0 + nc) = *(uint2*)o;
}

// ---------------- bf16 MFMA GEMM, global_load_lds + BK=64 XOR swizzle ----------------
// Grid: (M/BM, N/128) — m-tiles on x so same-weight blocks land on one XCD.
// EPI 0: qkv fused (q (pre-scaled by K2) / k -> qkv w/ L2-norm; v -> vt via LDS transpose)
// EPI 1: res + gate*0.5*v (fp32 out)   EPI 2: gelu tanh-form (bf16 out)   EPI 3: clip(res+gate*v,+-10) (fp32 out)
template<int EPI, int OBF, int BM>
__global__ __launch_bounds__(256)
void gemm_bf16(const unsigned short* __restrict__ A, const unsigned short* __restrict__ BT,
               const float* __restrict__ bias, const float* __restrict__ bias_b,
               const float* __restrict__ bias_c, const float* __restrict__ res,
               void* __restrict__ Cv, unsigned short* __restrict__ vtout,
               int M, int N, int K, const float* __restrict__ gate_p)
{
    constexpr int WN = (BM == 128) ? 2 : 4;
    constexpr int WSPAN = 128 / WN;
    constexpr int NT = WSPAN / 16;
    constexpr int MT = 4;
    constexpr int ACALLS = BM / 32;
    constexpr int SMEMSZ = (EPI == 0) ? 17408 : (BM * 64 + 128 * 64);
    __shared__ __align__(16) unsigned short SMEM[SMEMSZ];
    unsigned short* As = SMEM;
    unsigned short* Bs = SMEM + BM * 64;
    const int tid = threadIdx.x, w = tid >> 6, lane = tid & 63, quad = lane >> 4, ln = lane & 15;
    const int wm = w / WN, wn = w % WN;
    const int m0 = blockIdx.x * BM, n0 = blockIdx.y * 128;
    const int jg = (lane & 7) ^ ((lane >> 3) & 7);
    const int rb = w * 8 + (lane >> 3);
    const unsigned short* Agl = A + (size_t)(m0 + rb) * K + jg * 8;
    const unsigned short* Bgl = BT + (size_t)(n0 + rb) * K + jg * 8;

    fvec4 acc[MT][NT];
#pragma unroll
    for (int mt = 0; mt < MT; mt++)
#pragma unroll
        for (int nt = 0; nt < NT; nt++)
#pragma unroll
            for (int r = 0; r < 4; r++) acc[mt][nt][r] = 0.f;

    for (int k0 = 0; k0 < K; k0 += 64) {
        __syncthreads();
#pragma unroll
        for (int c = 0; c < ACALLS; c++)
            glds16(Agl + k0 + (size_t)c * 32 * K, As + c * 2048 + w * 512);
#pragma unroll
        for (int c = 0; c < 4; c++)
            glds16(Bgl + k0 + (size_t)c * 32 * K, Bs + c * 2048 + w * 512);
        __syncthreads();
#pragma unroll
        for (int kk = 0; kk < 2; kk++) {
            svec8 af[MT], bfr[NT];
#pragma unroll
            for (int mt = 0; mt < MT; mt++)
                af[mt] = FRAG(As, wm * 64 + mt * 16 + ln, kk * 4 + quad);
#pragma unroll
            for (int nt = 0; nt < NT; nt++)
                bfr[nt] = FRAG(Bs, wn * WSPAN + nt * 16 + ln, kk * 4 + quad);
#pragma unroll
            for (int mt = 0; mt < MT; mt++)
#pragma unroll
                for (int nt = 0; nt < NT; nt++)
                    acc[mt][nt] = mfma16(af[mt], bfr[nt], acc[mt][nt]);
        }
    }

    const float gate = (EPI == 1 || EPI == 3) ? gate_p[0] : 0.f;
    float bb[NT];
#pragma unroll
    for (int nt = 0; nt < NT; nt++) {
        int n = n0 + wn * WSPAN + nt * 16 + ln;
        if (EPI == 0) {
            int nseg = n >> 9;
            const float* bsel = nseg == 0 ? bias : (nseg == 1 ? bias_b : bias_c);
            bb[nt] = bsel[n - nseg * 512];
        } else {
            bb[nt] = bias[n];
        }
    }

    if (EPI == 0 && n0 >= 1024) {
        // ---- V path: bias + LDS transpose -> coalesced vt writes ----
        __syncthreads();                    // staging reads done; reuse SMEM
#pragma unroll
        for (int mt = 0; mt < MT; mt++) {
#pragma unroll
            for (int nt = 0; nt < NT; nt++) {
                int nl = wn * 64 + nt * 16 + ln;
                int mb = wm * 64 + mt * 16 + quad * 4;
                unsigned int lo = pk2b(acc[mt][nt][0] + bb[nt], acc[mt][nt][1] + bb[nt]);
                unsigned int hi = pk2b(acc[mt][nt][2] + bb[nt], acc[mt][nt][3] + bb[nt]);
                uint2 u; u.x = lo; u.y = hi;
                *(uint2*)(SMEM + nl * 136 + mb) = u;
            }
        }
        __syncthreads();
        int row = tid >> 1, half = (tid & 1) * 64;
        unsigned short* dst = vtout + ((size_t)((m0 >> 11) * 512 + (n0 - 1024) + row)) * T
                              + (m0 & (T - 1)) + half;
        const unsigned short* src = SMEM + row * 136 + half;
#pragma unroll
        for (int j = 0; j < 8; j++) *(uint4*)(dst + j * 8) = *(const uint4*)(src + j * 8);
        return;
    }

#pragma unroll
    for (int mt = 0; mt < MT; mt++) {
        float v[NT][4];
#pragma unroll
        for (int nt = 0; nt < NT; nt++)
#pragma unroll
            for (int r = 0; r < 4; r++) v[nt][r] = acc[mt][nt][r] + bb[nt];
        if (EPI == 0) {   // q/k: fused L2 norm; q additionally pre-scaled by K2
            const float fac = ((n0 + wn * WSPAN) < 512) ? K2 : 1.f;
#pragma unroll
            for (int r = 0; r < 4; r++) {
                float s = 0.f;
#pragma unroll
                for (int nt = 0; nt < NT; nt++) s += v[nt][r] * v[nt][r];
                s += __shfl_xor(s, 1); s += __shfl_xor(s, 2);
                s += __shfl_xor(s, 4); s += __shfl_xor(s, 8);
                float rs = fac / fmaxf(sqrtf(s), 1e-8f);
#pragma unroll
                for (int nt = 0; nt < NT; nt++) v[nt][r] *= rs;
            }
        }
#pragma unroll
        for (int nt = 0; nt < NT; nt++) {
            int n = n0 + wn * WSPAN + nt * 16 + ln;
#pragma unroll
            for (int r = 0; r < 4; r++) {
                int m = m0 + wm * 64 + mt * 16 + quad * 4 + r;
                float val = v[nt][r];
                if (EPI == 0) {
                    ((unsigned short*)Cv)[(size_t)m * QS2 + n] = f2b(val);
                } else {
                    size_t off = (size_t)m * N + n;
                    if (EPI == 1) val = res[off] + gate * 0.5f * val;
                    else if (EPI == 2) {
                        float u = val;
                        float z = 0.7978845608028654f * fmaf(0.044715f * u, u * u, u);
                        float e = __builtin_amdgcn_exp2f(z * 2.8853900817779268f);
                        float rr = __builtin_amdgcn_rcpf(e + 1.f);
                        val = u * (1.f - rr);
                    }
                    else if (EPI == 3) val = fminf(fmaxf(res[off] + gate * val, -10.f), 10.f);
                    if (OBF) ((unsigned short*)Cv)[off] = f2b(val);
                    else ((float*)Cv)[off] = val;
                }
            }
        }
    }
}

// ---------------- paired flash attention: merged A/B steps share K/V frags, Q in regs ----------------
template<bool MERGED, bool DIAGS>
__device__ __forceinline__ void attn_step2(
    unsigned short* PsA, unsigned short* PsB,
    const unsigned short* Ks, const unsigned short* Vt,
    svec8 qA0, svec8 qA1, svec8 qB0, svec8 qB1,
    bool diagA, bool diagB,
    fvec4 (&oA)[4], fvec4& lA, fvec4 (&oB)[4], fvec4& lB,
    int w, int quad, int ln)
{
    constexpr short BONE = (short)0x3F80;     // bf16 1.0
    const svec8 ONES8 = {BONE, BONE, BONE, BONE, BONE, BONE, BONE, BONE};
    const int qrow = w * 16 + ln;             // this lane's q row (as P row)
    const int prow_base = (qrow << 6);
#pragma unroll
    for (int nt = 0; nt < 4; nt++) {
        svec8 kf0 = FRAG(Ks, nt * 16 + ln, quad);
        svec8 kf1 = FRAG(Ks, nt * 16 + ln, 4 + quad);
        const int sbase = nt * 16 + quad * 4;
        const int paddr = prow_base | ((((sbase >> 3) ^ (qrow & 7))) << 3) | (sbase & 7);
        {   // B tile
            fvec4 z; z[0] = z[1] = z[2] = z[3] = 0.f;
            z = mfma16(kf0, qB0, z);
            z = mfma16(kf1, qB1, z);
            float p[4];
#pragma unroll
            for (int r = 0; r < 4; r++) {
                float y = z[r];
                float pv = fmaf(y, fmaf(y, 0.5f, 1.f), 1.f);   // e^y quadratic, |y|<=0.059
                if (DIAGS && diagB && (sbase + r > qrow)) pv = 0.f;
                p[r] = pv;
            }
            uint2 u; u.x = pk2b(p[0], p[1]); u.y = pk2b(p[2], p[3]);
            *(uint2*)(PsB + paddr) = u;
        }
        if (MERGED) {   // A tile reuses kf0/kf1
            fvec4 z; z[0] = z[1] = z[2] = z[3] = 0.f;
            z = mfma16(kf0, qA0, z);
            z = mfma16(kf1, qA1, z);
            float p[4];
#pragma unroll
            for (int r = 0; r < 4; r++) {
                float y = z[r];
                float pv = fmaf(y, fmaf(y, 0.5f, 1.f), 1.f);
                if (DIAGS && diagA && (sbase + r > qrow)) pv = 0.f;
                p[r] = pv;
            }
            uint2 u; u.x = pk2b(p[0], p[1]); u.y = pk2b(p[2], p[3]);
            *(uint2*)(PsA + paddr) = u;
        }
    }
#pragma unroll
    for (int ks = 0; ks < 2; ks++) {
        svec8 paB = FRAG(PsB, w * 16 + ln, ks * 4 + quad);
        lB = mfma16(paB, ONES8, lB);
        svec8 paA;
        if (MERGED) { paA = FRAG(PsA, w * 16 + ln, ks * 4 + quad); lA = mfma16(paA, ONES8, lA); }
#pragma unroll
        for (int nt = 0; nt < 4; nt++) {
            svec8 vf = FRAG(Vt, nt * 16 + ln, ks * 4 + quad);
            oB[nt] = mfma16(paB, vf, oB[nt]);
            if (MERGED) oA[nt] = mfma16(paA, vf, oA[nt]);
        }
    }
}

__global__ __launch_bounds__(256)
void attn_pair_kernel(const unsigned short* __restrict__ qkv, const unsigned short* __restrict__ vt,
                      unsigned short* __restrict__ o)
{
    // PsA/PsB double as the Q staging buffers (Q moves to regs at ph==0).
    __shared__ __align__(16) unsigned short PsA[4096], PsB[4096];
    __shared__ __align__(16) unsigned short K0[4096], V0[4096], K1[4096], V1[4096];
    // XCD-aware decode: blocks with same (id & 7) share an XCD; 4 heads per XCD ~= L2 size.
    const int fid = blockIdx.x;
    const int xcd = fid & 7, slot = fid >> 3;
    const int bh = xcd * 4 + (slot & 3);
    const int p = slot >> 2;
    const int b = bh >> 3, hh = bh & 7;
    const int qtA = p, qtB = 31 - p, nst = 32 - p;
    const int tid = threadIdx.x, w = tid >> 6, lane = tid & 63, quad = lane >> 4, ln = lane & 15;
    const int rl = lane >> 3, sl = lane & 7, jgz = sl ^ rl;
    const int w8 = w * 8;
    const int grow = w8 + rl;
    const unsigned short* qrow_p = qkv + ((size_t)(b * T) + grow) * QS2 + hh * 64 + jgz * 8;
    const unsigned short* krow_p = qrow_p + 512;
    const unsigned short* vrow_p = vt + ((size_t)(bh * 64) + grow) * T + jgz * 8;

    // stage both Q tiles into PsA/PsB (consumed into regs at ph==0, then buffers become Ps)
    glds16(qrow_p + (size_t)(qtA * 64) * QS2, PsA + w8 * 64);
    glds16(qrow_p + (size_t)(qtA * 64 + 32) * QS2, PsA + (w8 + 32) * 64);
    glds16(qrow_p + (size_t)(qtB * 64) * QS2, PsB + w8 * 64);
    glds16(qrow_p + (size_t)(qtB * 64 + 32) * QS2, PsB + (w8 + 32) * 64);

    svec8 qA0 = {}, qA1 = {}, qB0 = {}, qB1 = {};
    fvec4 oA[4], oB[4], lAv, lBv;
#pragma unroll
    for (int r = 0; r < 4; r++) { lAv[r] = 0.f; lBv[r] = 0.f; }
#pragma unroll
    for (int nt = 0; nt < 4; nt++)
#pragma unroll
        for (int r = 0; r < 4; r++) { oA[nt][r] = 0.f; oB[nt][r] = 0.f; }

    const int Nph = (nst + 1) >> 1;
    for (int ph = 0; ph < Nph; ph++) {
        const int s0 = 2 * ph, s1 = 2 * ph + 1;
        __syncthreads();   // all reads of K0/V0/K1/V1 from previous phase complete (also drains Q glds at ph0)
        glds16(krow_p + (size_t)(s0 * 64) * QS2, K0 + w8 * 64);
        glds16(krow_p + (size_t)(s0 * 64 + 32) * QS2, K0 + (w8 + 32) * 64);
        glds16(vrow_p + s0 * 64, V0 + w8 * 64);
        glds16(vrow_p + (size_t)32 * T + s0 * 64, V0 + (w8 + 32) * 64);
        if (s1 < nst) {
            glds16(krow_p + (size_t)(s1 * 64) * QS2, K1 + w8 * 64);
            glds16(krow_p + (size_t)(s1 * 64 + 32) * QS2, K1 + (w8 + 32) * 64);
            glds16(vrow_p + s1 * 64, V1 + w8 * 64);
            glds16(vrow_p + (size_t)32 * T + s1 * 64, V1 + (w8 + 32) * 64);
        }
        __syncthreads();   // vmcnt drained: staged data visible
        if (ph == 0) {     // pull Q fragments into registers (wave-private rows), freeing PsA/PsB
            qA0 = FRAG(PsA, w * 16 + ln, quad); qA1 = FRAG(PsA, w * 16 + ln, 4 + quad);
            qB0 = FRAG(PsB, w * 16 + ln, quad); qB1 = FRAG(PsB, w * 16 + ln, 4 + quad);
        }
        {   // step s0
            const bool doA = (s0 <= p), dA = (s0 == p), dB = (s0 == nst - 1);
            if (doA) {
                if (dA | dB) attn_step2<true , true >(PsA, PsB, K0, V0, qA0, qA1, qB0, qB1, dA, dB, oA, lAv, oB, lBv, w, quad, ln);
                else         attn_step2<true , false>(PsA, PsB, K0, V0, qA0, qA1, qB0, qB1, dA, dB, oA, lAv, oB, lBv, w, quad, ln);
            } else {
                if (dB)      attn_step2<false, true >(PsA, PsB, K0, V0, qA0, qA1, qB0, qB1, dA, dB, oA, lAv, oB, lBv, w, quad, ln);
                else         attn_step2<false, false>(PsA, PsB, K0, V0, qA0, qA1, qB0, qB1, dA, dB, oA, lAv, oB, lBv, w, quad, ln);
            }
        }
        if (s1 < nst) {   // step s1
            const bool doA = (s1 <= p), dA = (s1 == p), dB = (s1 == nst - 1);
            if (doA) {
                if (dA | dB) attn_step2<true , true >(PsA, PsB, K1, V1, qA0, qA1, qB0, qB1, dA, dB, oA, lAv, oB, lBv, w, quad, ln);
                else         attn_step2<true , false>(PsA, PsB, K1, V1, qA0, qA1, qB0, qB1, dA, dB, oA, lAv, oB, lBv, w, quad, ln);
            } else {
                if (dB)      attn_step2<false, true >(PsA, PsB, K1, V1, qA0, qA1, qB0, qB1, dA, dB, oA, lAv, oB, lBv, w, quad, ln);
                else         attn_step2<false, false>(PsA, PsB, K1, V1, qA0, qA1, qB0, qB1, dA, dB, oA, lAv, oB, lBv, w, quad, ln);
            }
        }
    }

    unsigned short* ogA = o + (size_t)(b * T + qtA * 64 + w * 16 + quad * 4) * D + hh * 64;
    unsigned short* ogB = o + (size_t)(b * T + qtB * 64 + w * 16 + quad * 4) * D + hh * 64;
#pragma unroll
    for (int r = 0; r < 4; r++) {
        float ia = 1.f / lAv[r], ib = 1.f / lBv[r];
#pragma unroll
        for (int nt = 0; nt < 4; nt++) {
            ogA[(size_t)r * D + nt * 16 + ln] = f2b(oA[nt][r] * ia);
            ogB[(size_t)r * D + nt * 16 + ln] = f2b(oB[nt][r] * ib);
        }
    }
}

// ---------------- masked-mean pool partials ----------------
__global__ __launch_bounds__(256)
void pool_kernel(const float* __restrict__ hn, const float* __restrict__ x, float* __restrict__ part)
{
    int b = blockIdx.x, ch = blockIdx.y, tid = threadIdx.x;
    int t0 = ch * 128;
    float s0 = 0.f, s1 = 0.f, cnt = 0.f;
    for (int tt = 0; tt < 128; tt++) {
        int t = t0 + tt;
        float xv = x[b * T + t];
        float m = (xv == -1.0f) ? 0.f : 1.f;
        cnt += m;
        const float* r = hn + ((size_t)(b * T + t)) * D;
        s0 += r[tid] * m;
        s1 += r[tid + 256] * m;
    }
    float* pr = part + (size_t)(b * 16 + ch) * 513;
    pr[tid] = s0; pr[tid + 256] = s1;
    if (tid == 0) pr[512] = cnt;
}

// ---------------- heads ----------------
__global__ __launch_bounds__(64)
void head_kernel(const float* __restrict__ part,
                 const float* __restrict__ bh_g, const float* __restrict__ bh_bl,
                 const float* __restrict__ ah_g, const float* __restrict__ ah_bl,
                 const float* __restrict__ ch_g, const float* __restrict__ ch_bl,
                 const float* __restrict__ bh_w, const float* __restrict__ bh_b2,
                 const float* __restrict__ ah_w, const float* __restrict__ ah_b2,
                 const float* __restrict__ ch_w, const float* __restrict__ ch_b2,
                 float* __restrict__ out)
{
    int b = blockIdx.x, lane = threadIdx.x;
    float cnt = 0.f;
    for (int c = 0; c < 16; c++) cnt += part[(size_t)(b * 16 + c) * 513 + 512];
    float denom = fmaxf(cnt, 1.f);
    float md[8];
    float s = 0.f, s2 = 0.f;
#pragma unroll
    for (int j = 0; j < 8; j++) {
        int d = j * 64 + lane;
        float acc = 0.f;
        for (int c = 0; c < 16; c++) acc += part[(size_t)(b * 16 + c) * 513 + d];
        md[j] = acc / denom;
        s += md[j]; s2 += md[j] * md[j];
    }
    s = wave_red_sum(s); s2 = wave_red_sum(s2);
    float mu = s * (1.f / 512.f);
    float var = s2 * (1.f / 512.f) - mu * mu;
    float rstd = 1.f / sqrtf(var + 1e-5f);
    float a0 = 0.f, a1 = 0.f, a2 = 0.f, a3 = 0.f;
#pragma unroll
    for (int j = 0; j < 8; j++) {
        int d = j * 64 + lane;
        float z = (md[j] - mu) * rstd;
        float zb = z * bh_g[d] + bh_bl[d];
        a0 += zb * bh_w[d * 2 + 0];
        a1 += zb * bh_w[d * 2 + 1];
        a2 += (z * ah_g[d] + ah_bl[d]) * ah_w[d];
        a3 += (z * ch_g[d] + ch_bl[d]) * ch_w[d];
    }
    a0 = wave_red_sum(a0); a1 = wave_red_sum(a1);
    a2 = wave_red_sum(a2); a3 = wave_red_sum(a3);
    if (lane == 0) {
        out[b * 4 + 0] = a0 + bh_b2[0];
        out[b * 4 + 1] = a1 + bh_b2[1];
        out[b * 4 + 2] = a2 + ah_b2[0];
        float t3 = a3 + ch_b2[0];
        out[b * 4 + 3] = 1.f / (1.f + expf(-t3));
    }
}

// ---------------- launch ----------------
extern "C" void kernel_launch(void* const* d_in, const int* in_sizes, int n_in,
                              void* d_out, int out_size, void* d_ws, size_t ws_size,
                              hipStream_t stream)
{
    const float* x      = (const float*)d_in[0];
    const float* ip_w   = (const float*)d_in[1];
    const float* ip_b   = (const float*)d_in[2];
    const float* ip_ln_g= (const float*)d_in[3];
    const float* ip_ln_b= (const float*)d_in[4];
    const float* pos    = (const float*)d_in[5];
    const float* pad_tok= (const float*)d_in[6];
    const float* Wq = (const float*)d_in[7];  const float* bq = (const float*)d_in[8];
    const float* Wk = (const float*)d_in[9];  const float* bk = (const float*)d_in[10];
    const float* Wv = (const float*)d_in[11]; const float* bv = (const float*)d_in[12];
    const float* Wo = (const float*)d_in[13]; const float* bo = (const float*)d_in[14];
    const float* ln1_g = (const float*)d_in[15]; const float* ln1_b = (const float*)d_in[16];
    const float* ln2_g = (const float*)d_in[17]; const float* ln2_b = (const float*)d_in[18];
    const float* W1 = (const float*)d_in[19]; const float* b1 = (const float*)d_in[20];
    const float* W2 = (const float*)d_in[21]; const float* b2 = (const float*)d_in[22];
    const float* gate1 = (const float*)d_in[23]; const float* gate2 = (const float*)d_in[24];
    const float* fn_g = (const float*)d_in[25]; const float* fn_b = (const float*)d_in[26];
    const float* bh_g  = (const float*)d_in[27]; const float* bh_bl = (const float*)d_in[28];
    const float* ah_g  = (const float*)d_in[29]; const float* ah_bl = (const float*)d_in[30];
    const float* ch_g  = (const float*)d_in[31]; const float* ch_bl = (const float*)d_in[32];
    const float* bh_w  = (const float*)d_in[33]; const float* bh_b2 = (const float*)d_in[34];
    const float* ah_w  = (const float*)d_in[35]; const float* ah_b2 = (const float*)d_in[36];
    const float* ch_w  = (const float*)d_in[37]; const float* ch_b2 = (const float*)d_in[38];

    char* ws = (char*)d_ws;
    float*          h     = (float*)ws;                       // 16 MB fp32 [8192][512]
    unsigned short* act_b = (unsigned short*)(ws + 16777216); // 8 MB bf16 [8192][512]
    unsigned short* qkv   = (unsigned short*)(ws + 25165824); // 16 MB bf16 [8192][1024] (q|k)
    unsigned short* mid_b = (unsigned short*)(ws + 41943040); // 32 MB bf16 [8192][2048]
    float*          xn_f  = (float*)(ws + 41943040);          // 16 MB alias (final LN only)
    unsigned short* wT    = (unsigned short*)(ws + 75497472); // 6 MB per-layer transposed weights
    unsigned short* vt    = (unsigned short*)(ws + 81788928); // 8 MB bf16 [4*512][2048]
    float*          part  = (float*)(ws + 90177536);
    float*          out   = (float*)d_out;

    unsigned short* wqT = wT;             // [1536][512] (q,k,v contiguous)
    unsigned short* wkT = wT + 262144;
    unsigned short* wvT = wT + 524288;
    unsigned short* woT = wT + 786432;
    unsigned short* w1T = wT + 1048576;   // [2048][512]
    unsigned short* w2T = wT + 2097152;   // [512][2048]

    embed_kernel<<<dim3(Bsz * T), dim3(64), 0, stream>>>(x, ip_w, ip_b, ip_ln_g, ip_ln_b, pos, pad_tok, h);

    for (int i = 0; i < Lnum; i++) {
        const size_t dd = (size_t)i * D * D;
        const size_t df = (size_t)i * D * DFF;
        // fused: weight conversion (3072 blocks) + ln1 (2048 blocks x 4 rows = 8192 rows)
        prep_kernel<<<dim3(5120), dim3(256), 0, stream>>>(Wq + dd, Wk + dd, Wv + dd, Wo + dd,
                                                          W1 + df, W2 + df,
                                                          wqT, wkT, wvT, woT, w1T, w2T,
                                                          h, act_b, ln1_g + i * D, ln1_b + i * D);
        gemm_bf16<0, 1, 128><<<dim3(64, 12), dim3(256), 0, stream>>>(act_b, wqT, bq + i * D, bk + i * D, bv + i * D,
                                                                     nullptr, qkv, vt, Bsz * T, 1536, D, nullptr);
        attn_pair_kernel<<<dim3(512), dim3(256), 0, stream>>>(qkv, vt, act_b);
        gemm_bf16<1, 0, 64><<<dim3(128, 4), dim3(256), 0, stream>>>(act_b, woT, bo + i * D, nullptr, nullptr,
                                                                    h, h, nullptr, Bsz * T, D, D, gate1 + i);
        ln_bf16_kernel<<<dim3(Bsz * T / 4), dim3(256), 0, stream>>>(h, act_b, ln2_g + i * D, ln2_b + i * D);
        gemm_bf16<2, 1, 128><<<dim3(64, 16), dim3(256), 0, stream>>>(act_b, w1T, b1 + i * DFF, nullptr, nullptr,
                                                                     nullptr, mid_b, nullptr, Bsz * T, DFF, D, nullptr);
        gemm_bf16<3, 0, 64><<<dim3(128, 4), dim3(256), 0, stream>>>(mid_b, w2T, b2 + i * D, nullptr, nullptr,
                                                                    h, h, nullptr, Bsz * T, D, DFF, gate2 + i);
    }

    ln_kernel<<<dim3(Bsz * T / 4), dim3(256), 0, stream>>>(h, xn_f, fn_g, fn_b);
    pool_kernel<<<dim3(Bsz, 16), dim3(256), 0, stream>>>(xn_f, x, part);
    head_kernel<<<dim3(Bsz), dim3(64), 0, stream>>>(part, bh_g, bh_bl, ah_g, ah_bl, ch_g, ch_bl,
                                                    bh_w, bh_b2, ah_w, ah_b2, ch_w, ch_b2, out);
}

// Round 9
// 1131.756 us; speedup vs baseline: 1.0119x; 1.0119x over previous
//
#include <hip/hip_runtime.h>
#include <hip/hip_bf16.h>
#include <math.h>

// ---------------- constants ----------------
constexpr int Bsz = 4, T = 2048, D = 512, H = 8, Lnum = 6, DFF = 2048, DK = 64;
constexpr int QS2 = 1024;                       // qkv row stride (q at 0, k at 512; v goes to vt)
constexpr float K2 = 0.08838834764831845f / 1.5f;  // softmax exponent scale (folded into q)

typedef __attribute__((ext_vector_type(8))) short svec8;   // 8 bf16 (4 VGPRs)
typedef __attribute__((ext_vector_type(4))) float fvec4;   // 4 fp32 acc

__device__ __forceinline__ fvec4 mfma16(svec8 a, svec8 b, fvec4 c) {
    return __builtin_amdgcn_mfma_f32_16x16x32_bf16(a, b, c, 0, 0, 0);
}
__device__ __forceinline__ unsigned short f2b(float f) {
    unsigned int u = __float_as_uint(f);
    u += 0x7fffu + ((u >> 16) & 1u);
    return (unsigned short)(u >> 16);
}
__device__ __forceinline__ unsigned int pk2b(float a, float b) {
    __hip_bfloat162 h = __float22bfloat162_rn(float2{a, b});
    return *(unsigned int*)&h;
}
__device__ __forceinline__ float wave_red_sum(float v) {
    for (int o = 32; o > 0; o >>= 1) v += __shfl_down(v, o, 64);
    return __shfl(v, 0, 64);
}
// async global->LDS, 16B per lane; lds base must be wave-uniform (HW adds lane*16)
__device__ __forceinline__ void glds16(const unsigned short* g, unsigned short* l) {
    __builtin_amdgcn_global_load_lds(
        (const __attribute__((address_space(1))) unsigned int*)g,
        (__attribute__((address_space(3))) unsigned int*)l, 16, 0, 0);
}
// swizzled-tile fragment read: 64-wide rows, chunk kq of row r at slot kq^(r&7)
#define FRAG(buf, row, kq) (*(const svec8*)((buf) + (((row) << 6) | ((((kq) ^ ((row) & 7))) << 3))))

// ---------------- embed (fp32 h) ----------------
__global__ __launch_bounds__(64)
void embed_kernel(const float* __restrict__ x, const float* __restrict__ ip_w,
                  const float* __restrict__ ip_b, const float* __restrict__ g,
                  const float* __restrict__ bta, const float* __restrict__ pos,
                  const float* __restrict__ pad_tok, float* __restrict__ h)
{
    int row = blockIdx.x;
    int t = row & (T - 1);
    int lane = threadIdx.x;
    float xv = x[row];
    float xc = fminf(fmaxf(xv, -10.f), 10.f);
    bool pad = (xc == -1.0f);
    float pre[8];
    float s = 0.f, s2 = 0.f;
#pragma unroll
    for (int j = 0; j < 8; j++) {
        int d = j * 64 + lane;
        float p = xc * ip_w[d] + ip_b[d];
        pre[j] = p; s += p; s2 += p * p;
    }
    s = wave_red_sum(s); s2 = wave_red_sum(s2);
    float m = s * (1.f / 512.f);
    float var = s2 * (1.f / 512.f) - m * m;
    float rstd = 1.f / sqrtf(var + 1e-5f);
#pragma unroll
    for (int j = 0; j < 8; j++) {
        int d = j * 64 + lane;
        float hv = (pre[j] - m) * rstd * g[d] + bta[d] + 0.1f * pos[(size_t)t * D + d];
        if (pad) hv = pad_tok[d];
        h[(size_t)row * D + d] = hv;
    }
}

// ---------------- LayerNorm fp32 -> fp32 (final), 4 rows/block ----------------
__global__ __launch_bounds__(256)
void ln_kernel(const float* __restrict__ in, float* __restrict__ out,
               const float* __restrict__ g, const float* __restrict__ b)
{
    int row = blockIdx.x * 4 + (threadIdx.x >> 6);
    int lane = threadIdx.x & 63;
    const float* r = in + (size_t)row * D;
    float4 v0 = ((const float4*)r)[lane];
    float4 v1 = ((const float4*)r)[lane + 64];
    float s = v0.x + v0.y + v0.z + v0.w + v1.x + v1.y + v1.z + v1.w;
    float s2 = v0.x*v0.x + v0.y*v0.y + v0.z*v0.z + v0.w*v0.w
             + v1.x*v1.x + v1.y*v1.y + v1.z*v1.z + v1.w*v1.w;
    s = wave_red_sum(s); s2 = wave_red_sum(s2);
    float m = s * (1.f / 512.f);
    float var = s2 * (1.f / 512.f) - m * m;
    float rstd = 1.f / sqrtf(var + 1e-5f);
    float4 g0 = ((const float4*)g)[lane], g1 = ((const float4*)g)[lane + 64];
    float4 b0 = ((const float4*)b)[lane], b1 = ((const float4*)b)[lane + 64];
    float4 o0, o1;
    o0.x = (v0.x - m) * rstd * g0.x + b0.x; o0.y = (v0.y - m) * rstd * g0.y + b0.y;
    o0.z = (v0.z - m) * rstd * g0.z + b0.z; o0.w = (v0.w - m) * rstd * g0.w + b0.w;
    o1.x = (v1.x - m) * rstd * g1.x + b1.x; o1.y = (v1.y - m) * rstd * g1.y + b1.y;
    o1.z = (v1.z - m) * rstd * g1.z + b1.z; o1.w = (v1.w - m) * rstd * g1.w + b1.w;
    ((float4*)(out + (size_t)row * D))[lane] = o0;
    ((float4*)(out + (size_t)row * D))[lane + 64] = o1;
}

// ---------------- device LN fp32 -> bf16 helper (one wave, one row) ----------------
__device__ __forceinline__ void ln_row_bf16(const float* __restrict__ in, unsigned short* __restrict__ out,
                                            const float* __restrict__ g, const float* __restrict__ b,
                                            int row, int lane)
{
    const float* r = in + (size_t)row * D;
    float4 v0 = ((const float4*)r)[lane];
    float4 v1 = ((const float4*)r)[lane + 64];
    float s = v0.x + v0.y + v0.z + v0.w + v1.x + v1.y + v1.z + v1.w;
    float s2 = v0.x*v0.x + v0.y*v0.y + v0.z*v0.z + v0.w*v0.w
             + v1.x*v1.x + v1.y*v1.y + v1.z*v1.z + v1.w*v1.w;
    s = wave_red_sum(s); s2 = wave_red_sum(s2);
    float m = s * (1.f / 512.f);
    float var = s2 * (1.f / 512.f) - m * m;
    float rstd = 1.f / sqrtf(var + 1e-5f);
    float4 g0 = ((const float4*)g)[lane], g1 = ((const float4*)g)[lane + 64];
    float4 b0 = ((const float4*)b)[lane], b1 = ((const float4*)b)[lane + 64];
    unsigned short o0[4], o1[4];
    o0[0] = f2b((v0.x - m) * rstd * g0.x + b0.x); o0[1] = f2b((v0.y - m) * rstd * g0.y + b0.y);
    o0[2] = f2b((v0.z - m) * rstd * g0.z + b0.z); o0[3] = f2b((v0.w - m) * rstd * g0.w + b0.w);
    o1[0] = f2b((v1.x - m) * rstd * g1.x + b1.x); o1[1] = f2b((v1.y - m) * rstd * g1.y + b1.y);
    o1[2] = f2b((v1.z - m) * rstd * g1.z + b1.z); o1[3] = f2b((v1.w - m) * rstd * g1.w + b1.w);
    *(uint2*)(out + (size_t)row * D + lane * 4) = *(uint2*)o0;
    *(uint2*)(out + (size_t)row * D + 256 + lane * 4) = *(uint2*)o1;
}

__global__ __launch_bounds__(256)
void ln_bf16_kernel(const float* __restrict__ in, unsigned short* __restrict__ out,
                    const float* __restrict__ g, const float* __restrict__ b)
{
    ln_row_bf16(in, out, g, b, blockIdx.x * 4 + (threadIdx.x >> 6), threadIdx.x & 63);
}

// ---------------- fused per-layer prep: wconv (bid<3072) + ln1 (bid in [3072,5120)) ----------------
__global__ __launch_bounds__(256)
void prep_kernel(const float* __restrict__ wq, const float* __restrict__ wk,
                 const float* __restrict__ wv, const float* __restrict__ wo,
                 const float* __restrict__ w1, const float* __restrict__ w2,
                 unsigned short* __restrict__ oq, unsigned short* __restrict__ ok,
                 unsigned short* __restrict__ ov, unsigned short* __restrict__ oo,
                 unsigned short* __restrict__ o1, unsigned short* __restrict__ o2,
                 const float* __restrict__ hin, unsigned short* __restrict__ lnout,
                 const float* __restrict__ ln_g, const float* __restrict__ ln_b)
{
    __shared__ float tile[32][33];
    int bid = blockIdx.x;
    if (bid >= 3072) {
        int row = (bid - 3072) * 4 + (threadIdx.x >> 6);
        ln_row_bf16(hin, lnout, ln_g, ln_b, row, threadIdx.x & 63);
        return;
    }
    const float* in; unsigned short* out; int K, N, kt, nt;
    if (bid < 1024) {
        int sel = bid >> 8, loc = bid & 255;
        in  = sel == 0 ? wq : sel == 1 ? wk : sel == 2 ? wv : wo;
        out = sel == 0 ? oq : sel == 1 ? ok : sel == 2 ? ov : oo;
        K = 512; N = 512; kt = loc >> 4; nt = loc & 15;
    } else if (bid < 2048) {
        int loc = bid - 1024; in = w1; out = o1; K = 512; N = 2048; kt = loc >> 6; nt = loc & 63;
    } else {
        int loc = bid - 2048; in = w2; out = o2; K = 2048; N = 512; kt = loc >> 4; nt = loc & 15;
    }
    int k0 = kt * 32, n0 = nt * 32;
    int t = threadIdx.x;
    int kr = t >> 3, nc = (t & 7) * 4;
    float4 v = *(const float4*)(in + (size_t)(k0 + kr) * N + n0 + nc);
    tile[kr][nc] = v.x; tile[kr][nc + 1] = v.y; tile[kr][nc + 2] = v.z; tile[kr][nc + 3] = v.w;
    __syncthreads();
    unsigned short o[4];
#pragma unroll
    for (int i = 0; i < 4; i++) o[i] = f2b(tile[nc + i][kr]);
    *(uint2*)(out + (size_t)(n0 + kr) * K + k0 + nc) = *(uint2*)o;
}

// ---------------- bf16 MFMA GEMM, global_load_lds + BK=64 XOR swizzle ----------------
// Grid: (M/BM, N/128) — m-tiles on x so same-weight blocks land on one XCD.
// EPI 0: qkv fused (q (pre-scaled by K2) / k -> qkv w/ L2-norm; v -> vt via LDS transpose)
// EPI 1: res + gate*0.5*v (fp32 out)   EPI 2: gelu tanh-form (bf16 out)   EPI 3: clip(res+gate*v,+-10) (fp32 out)
template<int EPI, int OBF, int BM>
__global__ __launch_bounds__(256)
void gemm_bf16(const unsigned short* __restrict__ A, const unsigned short* __restrict__ BT,
               const float* __restrict__ bias, const float* __restrict__ bias_b,
               const float* __restrict__ bias_c, const float* __restrict__ res,
               void* __restrict__ Cv, unsigned short* __restrict__ vtout,
               int M, int N, int K, const float* __restrict__ gate_p)
{
    constexpr int WN = (BM == 128) ? 2 : 4;
    constexpr int WSPAN = 128 / WN;
    constexpr int NT = WSPAN / 16;
    constexpr int MT = 4;
    constexpr int ACALLS = BM / 32;
    constexpr int SMEMSZ = (EPI == 0) ? 17408 : (BM * 64 + 128 * 64);
    __shared__ __align__(16) unsigned short SMEM[SMEMSZ];
    unsigned short* As = SMEM;
    unsigned short* Bs = SMEM + BM * 64;
    const int tid = threadIdx.x, w = tid >> 6, lane = tid & 63, quad = lane >> 4, ln = lane & 15;
    const int wm = w / WN, wn = w % WN;
    const int m0 = blockIdx.x * BM, n0 = blockIdx.y * 128;
    const int jg = (lane & 7) ^ ((lane >> 3) & 7);
    const int rb = w * 8 + (lane >> 3);
    const unsigned short* Agl = A + (size_t)(m0 + rb) * K + jg * 8;
    const unsigned short* Bgl = BT + (size_t)(n0 + rb) * K + jg * 8;

    fvec4 acc[MT][NT];
#pragma unroll
    for (int mt = 0; mt < MT; mt++)
#pragma unroll
        for (int nt = 0; nt < NT; nt++)
#pragma unroll
            for (int r = 0; r < 4; r++) acc[mt][nt][r] = 0.f;

    for (int k0 = 0; k0 < K; k0 += 64) {
        __syncthreads();
#pragma unroll
        for (int c = 0; c < ACALLS; c++)
            glds16(Agl + k0 + (size_t)c * 32 * K, As + c * 2048 + w * 512);
#pragma unroll
        for (int c = 0; c < 4; c++)
            glds16(Bgl + k0 + (size_t)c * 32 * K, Bs + c * 2048 + w * 512);
        __syncthreads();
#pragma unroll
        for (int kk = 0; kk < 2; kk++) {
            svec8 af[MT], bfr[NT];
#pragma unroll
            for (int mt = 0; mt < MT; mt++)
                af[mt] = FRAG(As, wm * 64 + mt * 16 + ln, kk * 4 + quad);
#pragma unroll
            for (int nt = 0; nt < NT; nt++)
                bfr[nt] = FRAG(Bs, wn * WSPAN + nt * 16 + ln, kk * 4 + quad);
#pragma unroll
            for (int mt = 0; mt < MT; mt++)
#pragma unroll
                for (int nt = 0; nt < NT; nt++)
                    acc[mt][nt] = mfma16(af[mt], bfr[nt], acc[mt][nt]);
        }
    }

    const float gate = (EPI == 1 || EPI == 3) ? gate_p[0] : 0.f;
    float bb[NT];
#pragma unroll
    for (int nt = 0; nt < NT; nt++) {
        int n = n0 + wn * WSPAN + nt * 16 + ln;
        if (EPI == 0) {
            int nseg = n >> 9;
            const float* bsel = nseg == 0 ? bias : (nseg == 1 ? bias_b : bias_c);
            bb[nt] = bsel[n - nseg * 512];
        } else {
            bb[nt] = bias[n];
        }
    }

    if (EPI == 0 && n0 >= 1024) {
        // ---- V path: bias + LDS transpose -> coalesced vt writes ----
        __syncthreads();                    // staging reads done; reuse SMEM
#pragma unroll
        for (int mt = 0; mt < MT; mt++) {
#pragma unroll
            for (int nt = 0; nt < NT; nt++) {
                int nl = wn * 64 + nt * 16 + ln;
                int mb = wm * 64 + mt * 16 + quad * 4;
                unsigned int lo = pk2b(acc[mt][nt][0] + bb[nt], acc[mt][nt][1] + bb[nt]);
                unsigned int hi = pk2b(acc[mt][nt][2] + bb[nt], acc[mt][nt][3] + bb[nt]);
                uint2 u; u.x = lo; u.y = hi;
                *(uint2*)(SMEM + nl * 136 + mb) = u;
            }
        }
        __syncthreads();
        int row = tid >> 1, half = (tid & 1) * 64;
        unsigned short* dst = vtout + ((size_t)((m0 >> 11) * 512 + (n0 - 1024) + row)) * T
                              + (m0 & (T - 1)) + half;
        const unsigned short* src = SMEM + row * 136 + half;
#pragma unroll
        for (int j = 0; j < 8; j++) *(uint4*)(dst + j * 8) = *(const uint4*)(src + j * 8);
        return;
    }

#pragma unroll
    for (int mt = 0; mt < MT; mt++) {
        float v[NT][4];
#pragma unroll
        for (int nt = 0; nt < NT; nt++)
#pragma unroll
            for (int r = 0; r < 4; r++) v[nt][r] = acc[mt][nt][r] + bb[nt];
        if (EPI == 0) {   // q/k: fused L2 norm; q additionally pre-scaled by K2
            const float fac = ((n0 + wn * WSPAN) < 512) ? K2 : 1.f;
#pragma unroll
            for (int r = 0; r < 4; r++) {
                float s = 0.f;
#pragma unroll
                for (int nt = 0; nt < NT; nt++) s += v[nt][r] * v[nt][r];
                s += __shfl_xor(s, 1); s += __shfl_xor(s, 2);
                s += __shfl_xor(s, 4); s += __shfl_xor(s, 8);
                float rs = fac / fmaxf(sqrtf(s), 1e-8f);
#pragma unroll
                for (int nt = 0; nt < NT; nt++) v[nt][r] *= rs;
            }
        }
#pragma unroll
        for (int nt = 0; nt < NT; nt++) {
            int n = n0 + wn * WSPAN + nt * 16 + ln;
#pragma unroll
            for (int r = 0; r < 4; r++) {
                int m = m0 + wm * 64 + mt * 16 + quad * 4 + r;
                float val = v[nt][r];
                if (EPI == 0) {
                    ((unsigned short*)Cv)[(size_t)m * QS2 + n] = f2b(val);
                } else {
                    size_t off = (size_t)m * N + n;
                    if (EPI == 1) val = res[off] + gate * 0.5f * val;
                    else if (EPI == 2) {
                        float u = val;
                        float z = 0.7978845608028654f * fmaf(0.044715f * u, u * u, u);
                        float e = __builtin_amdgcn_exp2f(z * 2.8853900817779268f);
                        float rr = __builtin_amdgcn_rcpf(e + 1.f);
                        val = u * (1.f - rr);
                    }
                    else if (EPI == 3) val = fminf(fmaxf(res[off] + gate * val, -10.f), 10.f);
                    if (OBF) ((unsigned short*)Cv)[off] = f2b(val);
                    else ((float*)Cv)[off] = val;
                }
            }
        }
    }
}

// ---------------- paired flash attention: 4 s-tiles per barrier phase ----------------
template<bool MERGED, bool DIAGS>
__device__ __forceinline__ void attn_step2(
    unsigned short* PsA, unsigned short* PsB,
    const unsigned short* Ks, const unsigned short* Vt,
    svec8 qA0, svec8 qA1, svec8 qB0, svec8 qB1,
    bool diagA, bool diagB,
    fvec4 (&oA)[4], fvec4& lA, fvec4 (&oB)[4], fvec4& lB,
    int w, int quad, int ln)
{
    constexpr short BONE = (short)0x3F80;     // bf16 1.0
    const svec8 ONES8 = {BONE, BONE, BONE, BONE, BONE, BONE, BONE, BONE};
    const int qrow = w * 16 + ln;             // this lane's q row (as P row)
    const int prow_base = (qrow << 6);
#pragma unroll
    for (int nt = 0; nt < 4; nt++) {
        svec8 kf0 = FRAG(Ks, nt * 16 + ln, quad);
        svec8 kf1 = FRAG(Ks, nt * 16 + ln, 4 + quad);
        const int sbase = nt * 16 + quad * 4;
        const int paddr = prow_base | ((((sbase >> 3) ^ (qrow & 7))) << 3) | (sbase & 7);
        {   // B tile
            fvec4 z; z[0] = z[1] = z[2] = z[3] = 0.f;
            z = mfma16(kf0, qB0, z);
            z = mfma16(kf1, qB1, z);
            float p[4];
#pragma unroll
            for (int r = 0; r < 4; r++) {
                float y = z[r];
                float pv = fmaf(y, fmaf(y, 0.5f, 1.f), 1.f);   // e^y quadratic, |y|<=0.059
                if (DIAGS && diagB && (sbase + r > qrow)) pv = 0.f;
                p[r] = pv;
            }
            uint2 u; u.x = pk2b(p[0], p[1]); u.y = pk2b(p[2], p[3]);
            *(uint2*)(PsB + paddr) = u;
        }
        if (MERGED) {   // A tile reuses kf0/kf1
            fvec4 z; z[0] = z[1] = z[2] = z[3] = 0.f;
            z = mfma16(kf0, qA0, z);
            z = mfma16(kf1, qA1, z);
            float p[4];
#pragma unroll
            for (int r = 0; r < 4; r++) {
                float y = z[r];
                float pv = fmaf(y, fmaf(y, 0.5f, 1.f), 1.f);
                if (DIAGS && diagA && (sbase + r > qrow)) pv = 0.f;
                p[r] = pv;
            }
            uint2 u; u.x = pk2b(p[0], p[1]); u.y = pk2b(p[2], p[3]);
            *(uint2*)(PsA + paddr) = u;
        }
    }
#pragma unroll
    for (int ks = 0; ks < 2; ks++) {
        svec8 paB = FRAG(PsB, w * 16 + ln, ks * 4 + quad);
        lB = mfma16(paB, ONES8, lB);
        svec8 paA;
        if (MERGED) { paA = FRAG(PsA, w * 16 + ln, ks * 4 + quad); lA = mfma16(paA, ONES8, lA); }
#pragma unroll
        for (int nt = 0; nt < 4; nt++) {
            svec8 vf = FRAG(Vt, nt * 16 + ln, ks * 4 + quad);
            oB[nt] = mfma16(paB, vf, oB[nt]);
            if (MERGED) oA[nt] = mfma16(paA, vf, oA[nt]);
        }
    }
}

// dispatcher: picks MERGED/DIAGS template variant for step s
__device__ __forceinline__ void attn_do_step(
    int s, int p, int nst,
    unsigned short* PsA, unsigned short* PsB,
    const unsigned short* Ks, const unsigned short* Vt,
    svec8 qA0, svec8 qA1, svec8 qB0, svec8 qB1,
    fvec4 (&oA)[4], fvec4& lA, fvec4 (&oB)[4], fvec4& lB,
    int w, int quad, int ln)
{
    const bool doA = (s <= p), dA = (s == p), dB = (s == nst - 1);
    if (doA) {
        if (dA | dB) attn_step2<true , true >(PsA, PsB, Ks, Vt, qA0, qA1, qB0, qB1, dA, dB, oA, lA, oB, lB, w, quad, ln);
        else         attn_step2<true , false>(PsA, PsB, Ks, Vt, qA0, qA1, qB0, qB1, dA, dB, oA, lA, oB, lB, w, quad, ln);
    } else {
        if (dB)      attn_step2<false, true >(PsA, PsB, Ks, Vt, qA0, qA1, qB0, qB1, dA, dB, oA, lA, oB, lB, w, quad, ln);
        else         attn_step2<false, false>(PsA, PsB, Ks, Vt, qA0, qA1, qB0, qB1, dA, dB, oA, lA, oB, lB, w, quad, ln);
    }
}

__global__ __launch_bounds__(256)
void attn_pair_kernel(const unsigned short* __restrict__ qkv, const unsigned short* __restrict__ vt,
                      unsigned short* __restrict__ o)
{
    // PsA/PsB double as the Q staging buffers (Q moves to regs at ph==0).
    // 4 K/V tile-slots per barrier phase: 10 x 8KB = 80 KB (grid caps occupancy at 2/CU anyway).
    __shared__ __align__(16) unsigned short PsA[4096], PsB[4096];
    __shared__ __align__(16) unsigned short Kb[4][4096], Vb[4][4096];
    // XCD-aware decode: blocks with same (id & 7) share an XCD; 4 heads per XCD ~= L2 size.
    const int fid = blockIdx.x;
    const int xcd = fid & 7, slot = fid >> 3;
    const int bh = xcd * 4 + (slot & 3);
    const int p = slot >> 2;
    const int b = bh >> 3, hh = bh & 7;
    const int qtA = p, qtB = 31 - p, nst = 32 - p;
    const int tid = threadIdx.x, w = tid >> 6, lane = tid & 63, quad = lane >> 4, ln = lane & 15;
    const int rl = lane >> 3, sl = lane & 7, jgz = sl ^ rl;
    const int w8 = w * 8;
    const int grow = w8 + rl;
    const unsigned short* qrow_p = qkv + ((size_t)(b * T) + grow) * QS2 + hh * 64 + jgz * 8;
    const unsigned short* krow_p = qrow_p + 512;
    const unsigned short* vrow_p = vt + ((size_t)(bh * 64) + grow) * T + jgz * 8;

    // stage both Q tiles into PsA/PsB (consumed into regs at ph==0, then buffers become Ps)
    glds16(qrow_p + (size_t)(qtA * 64) * QS2, PsA + w8 * 64);
    glds16(qrow_p + (size_t)(qtA * 64 + 32) * QS2, PsA + (w8 + 32) * 64);
    glds16(qrow_p + (size_t)(qtB * 64) * QS2, PsB + w8 * 64);
    glds16(qrow_p + (size_t)(qtB * 64 + 32) * QS2, PsB + (w8 + 32) * 64);

    svec8 qA0 = {}, qA1 = {}, qB0 = {}, qB1 = {};
    fvec4 oA[4], oB[4], lAv, lBv;
#pragma unroll
    for (int r = 0; r < 4; r++) { lAv[r] = 0.f; lBv[r] = 0.f; }
#pragma unroll
    for (int nt = 0; nt < 4; nt++)
#pragma unroll
        for (int r = 0; r < 4; r++) { oA[nt][r] = 0.f; oB[nt][r] = 0.f; }

    const int Nph = (nst + 3) >> 2;
    for (int ph = 0; ph < Nph; ph++) {
        const int sb = 4 * ph;
        __syncthreads();   // all reads of Kb/Vb from previous phase complete (also drains Q glds at ph0)
#pragma unroll
        for (int i = 0; i < 4; i++) {
            const int s = sb + i;
            if (s < nst) {
                glds16(krow_p + (size_t)(s * 64) * QS2, Kb[i] + w8 * 64);
                glds16(krow_p + (size_t)(s * 64 + 32) * QS2, Kb[i] + (w8 + 32) * 64);
                glds16(vrow_p + s * 64, Vb[i] + w8 * 64);
                glds16(vrow_p + (size_t)32 * T + s * 64, Vb[i] + (w8 + 32) * 64);
            }
        }
        __syncthreads();   // vmcnt drained: staged data visible
        if (ph == 0) {     // pull Q fragments into registers (wave-private rows), freeing PsA/PsB
            qA0 = FRAG(PsA, w * 16 + ln, quad); qA1 = FRAG(PsA, w * 16 + ln, 4 + quad);
            qB0 = FRAG(PsB, w * 16 + ln, quad); qB1 = FRAG(PsB, w * 16 + ln, 4 + quad);
        }
#pragma unroll
        for (int i = 0; i < 4; i++) {
            const int s = sb + i;
            if (s < nst)
                attn_do_step(s, p, nst, PsA, PsB, Kb[i], Vb[i],
                             qA0, qA1, qB0, qB1, oA, lAv, oB, lBv, w, quad, ln);
        }
    }

    unsigned short* ogA = o + (size_t)(b * T + qtA * 64 + w * 16 + quad * 4) * D + hh * 64;
    unsigned short* ogB = o + (size_t)(b * T + qtB * 64 + w * 16 + quad * 4) * D + hh * 64;
#pragma unroll
    for (int r = 0; r < 4; r++) {
        float ia = 1.f / lAv[r], ib = 1.f / lBv[r];
#pragma unroll
        for (int nt = 0; nt < 4; nt++) {
            ogA[(size_t)r * D + nt * 16 + ln] = f2b(oA[nt][r] * ia);
            ogB[(size_t)r * D + nt * 16 + ln] = f2b(oB[nt][r] * ib);
        }
    }
}

// ---------------- masked-mean pool partials ----------------
__global__ __launch_bounds__(256)
void pool_kernel(const float* __restrict__ hn, const float* __restrict__ x, float* __restrict__ part)
{
    int b = blockIdx.x, ch = blockIdx.y, tid = threadIdx.x;
    int t0 = ch * 128;
    float s0 = 0.f, s1 = 0.f, cnt = 0.f;
    for (int tt = 0; tt < 128; tt++) {
        int t = t0 + tt;
        float xv = x[b * T + t];
        float m = (xv == -1.0f) ? 0.f : 1.f;
        cnt += m;
        const float* r = hn + ((size_t)(b * T + t)) * D;
        s0 += r[tid] * m;
        s1 += r[tid + 256] * m;
    }
    float* pr = part + (size_t)(b * 16 + ch) * 513;
    pr[tid] = s0; pr[tid + 256] = s1;
    if (tid == 0) pr[512] = cnt;
}

// ---------------- heads ----------------
__global__ __launch_bounds__(64)
void head_kernel(const float* __restrict__ part,
                 const float* __restrict__ bh_g, const float* __restrict__ bh_bl,
                 const float* __restrict__ ah_g, const float* __restrict__ ah_bl,
                 const float* __restrict__ ch_g, const float* __restrict__ ch_bl,
                 const float* __restrict__ bh_w, const float* __restrict__ bh_b2,
                 const float* __restrict__ ah_w, const float* __restrict__ ah_b2,
                 const float* __restrict__ ch_w, const float* __restrict__ ch_b2,
                 float* __restrict__ out)
{
    int b = blockIdx.x, lane = threadIdx.x;
    float cnt = 0.f;
    for (int c = 0; c < 16; c++) cnt += part[(size_t)(b * 16 + c) * 513 + 512];
    float denom = fmaxf(cnt, 1.f);
    float md[8];
    float s = 0.f, s2 = 0.f;
#pragma unroll
    for (int j = 0; j < 8; j++) {
        int d = j * 64 + lane;
        float acc = 0.f;
        for (int c = 0; c < 16; c++) acc += part[(size_t)(b * 16 + c) * 513 + d];
        md[j] = acc / denom;
        s += md[j]; s2 += md[j] * md[j];
    }
    s = wave_red_sum(s); s2 = wave_red_sum(s2);
    float mu = s * (1.f / 512.f);
    float var = s2 * (1.f / 512.f) - mu * mu;
    float rstd = 1.f / sqrtf(var + 1e-5f);
    float a0 = 0.f, a1 = 0.f, a2 = 0.f, a3 = 0.f;
#pragma unroll
    for (int j = 0; j < 8; j++) {
        int d = j * 64 + lane;
        float z = (md[j] - mu) * rstd;
        float zb = z * bh_g[d] + bh_bl[d];
        a0 += zb * bh_w[d * 2 + 0];
        a1 += zb * bh_w[d * 2 + 1];
        a2 += (z * ah_g[d] + ah_bl[d]) * ah_w[d];
        a3 += (z * ch_g[d] + ch_bl[d]) * ch_w[d];
    }
    a0 = wave_red_sum(a0); a1 = wave_red_sum(a1);
    a2 = wave_red_sum(a2); a3 = wave_red_sum(a3);
    if (lane == 0) {
        out[b * 4 + 0] = a0 + bh_b2[0];
        out[b * 4 + 1] = a1 + bh_b2[1];
        out[b * 4 + 2] = a2 + ah_b2[0];
        float t3 = a3 + ch_b2[0];
        out[b * 4 + 3] = 1.f / (1.f + expf(-t3));
    }
}

// ---------------- launch ----------------
extern "C" void kernel_launch(void* const* d_in, const int* in_sizes, int n_in,
                              void* d_out, int out_size, void* d_ws, size_t ws_size,
                              hipStream_t stream)
{
    const float* x      = (const float*)d_in[0];
    const float* ip_w   = (const float*)d_in[1];
    const float* ip_b   = (const float*)d_in[2];
    const float* ip_ln_g= (const float*)d_in[3];
    const float* ip_ln_b= (const float*)d_in[4];
    const float* pos    = (const float*)d_in[5];
    const float* pad_tok= (const float*)d_in[6];
    const float* Wq = (const float*)d_in[7];  const float* bq = (const float*)d_in[8];
    const float* Wk = (const float*)d_in[9];  const float* bk = (const float*)d_in[10];
    const float* Wv = (const float*)d_in[11]; const float* bv = (const float*)d_in[12];
    const float* Wo = (const float*)d_in[13]; const float* bo = (const float*)d_in[14];
    const float* ln1_g = (const float*)d_in[15]; const float* ln1_b = (const float*)d_in[16];
    const float* ln2_g = (const float*)d_in[17]; const float* ln2_b = (const float*)d_in[18];
    const float* W1 = (const float*)d_in[19]; const float* b1 = (const float*)d_in[20];
    const float* W2 = (const float*)d_in[21]; const float* b2 = (const float*)d_in[22];
    const float* gate1 = (const float*)d_in[23]; const float* gate2 = (const float*)d_in[24];
    const float* fn_g = (const float*)d_in[25]; const float* fn_b = (const float*)d_in[26];
    const float* bh_g  = (const float*)d_in[27]; const float* bh_bl = (const float*)d_in[28];
    const float* ah_g  = (const float*)d_in[29]; const float* ah_bl = (const float*)d_in[30];
    const float* ch_g  = (const float*)d_in[31]; const float* ch_bl = (const float*)d_in[32];
    const float* bh_w  = (const float*)d_in[33]; const float* bh_b2 = (const float*)d_in[34];
    const float* ah_w  = (const float*)d_in[35]; const float* ah_b2 = (const float*)d_in[36];
    const float* ch_w  = (const float*)d_in[37]; const float* ch_b2 = (const float*)d_in[38];

    char* ws = (char*)d_ws;
    float*          h     = (float*)ws;                       // 16 MB fp32 [8192][512]
    unsigned short* act_b = (unsigned short*)(ws + 16777216); // 8 MB bf16 [8192][512]
    unsigned short* qkv   = (unsigned short*)(ws + 25165824); // 16 MB bf16 [8192][1024] (q|k)
    unsigned short* mid_b = (unsigned short*)(ws + 41943040); // 32 MB bf16 [8192][2048]
    float*          xn_f  = (float*)(ws + 41943040);          // 16 MB alias (final LN only)
    unsigned short* wT    = (unsigned short*)(ws + 75497472); // 6 MB per-layer transposed weights
    unsigned short* vt    = (unsigned short*)(ws + 81788928); // 8 MB bf16 [4*512][2048]
    float*          part  = (float*)(ws + 90177536);
    float*          out   = (float*)d_out;

    unsigned short* wqT = wT;             // [1536][512] (q,k,v contiguous)
    unsigned short* wkT = wT + 262144;
    unsigned short* wvT = wT + 524288;
    unsigned short* woT = wT + 786432;
    unsigned short* w1T = wT + 1048576;   // [2048][512]
    unsigned short* w2T = wT + 2097152;   // [512][2048]

    embed_kernel<<<dim3(Bsz * T), dim3(64), 0, stream>>>(x, ip_w, ip_b, ip_ln_g, ip_ln_b, pos, pad_tok, h);

    for (int i = 0; i < Lnum; i++) {
        const size_t dd = (size_t)i * D * D;
        const size_t df = (size_t)i * D * DFF;
        // fused: weight conversion (3072 blocks) + ln1 (2048 blocks x 4 rows = 8192 rows)
        prep_kernel<<<dim3(5120), dim3(256), 0, stream>>>(Wq + dd, Wk + dd, Wv + dd, Wo + dd,
                                                          W1 + df, W2 + df,
                                                          wqT, wkT, wvT, woT, w1T, w2T,
                                                          h, act_b, ln1_g + i * D, ln1_b + i * D);
        gemm_bf16<0, 1, 128><<<dim3(64, 12), dim3(256), 0, stream>>>(act_b, wqT, bq + i * D, bk + i * D, bv + i * D,
                                                                     nullptr, qkv, vt, Bsz * T, 1536, D, nullptr);
        attn_pair_kernel<<<dim3(512), dim3(256), 0, stream>>>(qkv, vt, act_b);
        gemm_bf16<1, 0, 64><<<dim3(128, 4), dim3(256), 0, stream>>>(act_b, woT, bo + i * D, nullptr, nullptr,
                                                                    h, h, nullptr, Bsz * T, D, D, gate1 + i);
        ln_bf16_kernel<<<dim3(Bsz * T / 4), dim3(256), 0, stream>>>(h, act_b, ln2_g + i * D, ln2_b + i * D);
        gemm_bf16<2, 1, 128><<<dim3(64, 16), dim3(256), 0, stream>>>(act_b, w1T, b1 + i * DFF, nullptr, nullptr,
                                                                     nullptr, mid_b, nullptr, Bsz * T, DFF, D, nullptr);
        gemm_bf16<3, 0, 64><<<dim3(128, 4), dim3(256), 0, stream>>>(mid_b, w2T, b2 + i * D, nullptr, nullptr,
                                                                    h, h, nullptr, Bsz * T, D, DFF, gate2 + i);
    }

    ln_kernel<<<dim3(Bsz * T / 4), dim3(256), 0, stream>>>(h, xn_f, fn_g, fn_b);
    pool_kernel<<<dim3(Bsz, 16), dim3(256), 0, stream>>>(xn_f, x, part);
    head_kernel<<<dim3(Bsz), dim3(64), 0, stream>>>(part, bh_g, bh_bl, ah_g, ah_bl, ch_g, ch_bl,
                                                    bh_w, bh_b2, ah_w, ah_b2, ch_w, ch_b2, out);
}